// Round 7
// baseline (249.893 us; speedup 1.0000x reference)
//
#include <hip/hip_runtime.h>

#define NB 16
#define NC 64
#define C2 32
#define C4 16
#define HH 256
#define WW 256
#define HW (HH*WW)          // 65536

typedef float f4 __attribute__((ext_vector_type(4)));

// ws layout (floats):
//   [0, 2048)        w1T   : w1T[c*32+o] = w1[o*64+c]
//   [2048, 10240)    S1    : [b][o32][s16]   (per-b stride 512)
//   [10240, 18432)   S2
//   [18432, 26624)   S3
//   [26624, 30720)   gates : [b][o16][s16]   (per-b stride 256)

__global__ __launch_bounds__(256) void prep_kernel(const float* __restrict__ w1,
                                                   float* __restrict__ ws) {
    int t = threadIdx.x;
    for (int i = t; i < 24576; i += 256) ws[2048 + i] = 0.f;
    for (int i = t; i < 2048; i += 256) {
        int o = i >> 6, c = i & 63;
        ws[c * 32 + o] = w1[i];
    }
}

__device__ __forceinline__ void gl_lds16(const float* g, float* l) {
    __builtin_amdgcn_global_load_lds(
        (const __attribute__((address_space(1))) unsigned int*)g,
        (__attribute__((address_space(3))) unsigned int*)l,
        16, 0, 0);
}

// Stats: S1,S2,S3 per (b, o in [0,32), s in [0,16)).
// Block = (b, r=h%4, 8-row chunk, 64-col segment). Waves split o (8 each).
// x staged via 16KB double-buffered LDS (global_load_lds, counted vmcnt).
// Weights preloaded to LDS; inner loop is PURE DS (no SMEM -> no lgkmcnt
// cross-queue drains): per c = 1 ds_read_b32 (x) + 2 ds_read_b128 (w, wave-
// uniform broadcast) + 8 FMA.
__global__ __launch_bounds__(256) void stats_kernel(const float* __restrict__ x,
                                                    const float* __restrict__ w1t,
                                                    const float* __restrict__ b1,
                                                    float* __restrict__ stats) {
    __shared__ float sbuf[2][64 * 64];   // 2 x 16KB
    __shared__ float wlds[2048];         // 8KB: [c][32] weights

    int bid   = blockIdx.x;
    int b     = bid >> 7;          // 128 blocks per batch
    int rest  = bid & 127;
    int r     = rest >> 5;         // h residue 0..3
    int rest2 = rest & 31;
    int chunk = rest2 >> 2;        // 8 row-chunks (8 rows each)
    int colc  = rest2 & 3;         // 4 column segments of 64
    int t     = threadIdx.x;
    int lane  = t & 63;            // column within segment
    int wid   = t >> 6;            // wave id = o-group
    int ogs   = __builtin_amdgcn_readfirstlane(wid);

    const float* xseg = x + (size_t)b * NC * HW + colc * 64;

    // Stage row p into sbuf[p&1]: wave wid stages channels wid*16 .. wid*16+15.
#define STAGE(p_) do {                                                         \
        int h_ = r + 4 * (chunk * 8 + (p_));                                   \
        const float* gs_ = xseg + (size_t)h_ * WW;                             \
        float* ls_ = &sbuf[(p_) & 1][0];                                       \
        _Pragma("unroll")                                                      \
        for (int k_ = 0; k_ < 4; ++k_) {                                       \
            int c0_ = wid * 16 + k_ * 4;                                       \
            gl_lds16(gs_ + (size_t)(c0_ + (lane >> 4)) * HW + (lane & 15) * 4, \
                     ls_ + c0_ * 64);                                          \
        }                                                                      \
    } while (0)

    STAGE(0);

    // Preload weights + bias while stage 0 is in flight.
    {
        f4* wl4 = (f4*)wlds;
        const f4* wg4 = (const f4*)w1t;
        wl4[t * 2]     = wg4[t * 2];
        wl4[t * 2 + 1] = wg4[t * 2 + 1];
    }
    float bias[8];
    #pragma unroll
    for (int o = 0; o < 8; o++) bias[o] = b1[ogs * 8 + o];
    __syncthreads();   // weights visible (also drains stage-0 loads; harmless)

    float S1[8], S2[8], S3[8];
    #pragma unroll
    for (int o = 0; o < 8; o++) { S1[o] = 0.f; S2[o] = 0.f; S3[o] = 0.f; }

    const f4* wrow = (const f4*)wlds;   // index c*8 + ogs*2 (+1)

    #pragma unroll 1
    for (int p = 0; p < 8; ++p) {
        if (p < 7) {
            STAGE(p + 1);
            asm volatile("s_waitcnt vmcnt(4)" ::: "memory");   // stage p landed
        } else {
            asm volatile("s_waitcnt vmcnt(0)" ::: "memory");
        }
        __builtin_amdgcn_s_barrier();

        const float* L = &sbuf[p & 1][0];
        float acc[8];
        #pragma unroll
        for (int o = 0; o < 8; o++) acc[o] = bias[o];
        #pragma unroll
        for (int c = 0; c < 64; ++c) {
            float xc = L[c * 64 + lane];
            f4 wa = wrow[c * 8 + ogs * 2];
            f4 wb = wrow[c * 8 + ogs * 2 + 1];
            acc[0] += wa[0] * xc;  acc[1] += wa[1] * xc;
            acc[2] += wa[2] * xc;  acc[3] += wa[3] * xc;
            acc[4] += wb[0] * xc;  acc[5] += wb[1] * xc;
            acc[6] += wb[2] * xc;  acc[7] += wb[3] * xc;
        }
        #pragma unroll
        for (int o = 0; o < 8; o++) {
            float v = fmaxf(acc[o], 0.f);
            float pw = v * v;
            S1[o] += v;
            S2[o] += pw;
            S3[o] += pw * v;
        }
        __builtin_amdgcn_s_barrier();   // reads of sbuf[p&1] done before restage
    }
#undef STAGE

    // Sum over the 16 lanes sharing (lane & 3); lanes 0..3 hold s4 = lane.
    #pragma unroll
    for (int o = 0; o < 8; o++) {
        float a = S1[o], bb = S2[o], cc = S3[o];
        #pragma unroll
        for (int m = 4; m <= 32; m <<= 1) {
            a  += __shfl_xor(a,  m);
            bb += __shfl_xor(bb, m);
            cc += __shfl_xor(cc, m);
        }
        if (lane < 4) {
            int idx = b * 512 + (ogs * 8 + o) * 16 + r * 4 + lane;
            atomicAdd(&stats[idx],         a);
            atomicAdd(&stats[8192 + idx],  bb);
            atomicAdd(&stats[16384 + idx], cc);
        }
    }
}

// Tiny attention: qkv = mean + m3; softmax(q q^T) @ v; gate = sigmoid(y).
__global__ __launch_bounds__(512) void attn_kernel(const float* __restrict__ stats,
                                                   float* __restrict__ gates) {
    int b = blockIdx.x;
    int t = threadIdx.x;
    __shared__ float qkv[512];
    {
        int idx = b * 512 + t;
        float S1 = stats[idx];
        float S2 = stats[8192 + idx];
        float S3 = stats[16384 + idx];
        float mu = S1 * (1.f / 4096.f);
        float m3 = (S3 - 3.f * mu * S2 + 2.f * 4096.f * mu * mu * mu) * (1.f / 16.f);
        qkv[t] = mu + m3;
    }
    __syncthreads();
    if (t < 256) {
        int o = t >> 4, s = t & 15;
        float qs = qkv[o * 16 + s];
        float mx = -1e30f;
        #pragma unroll
        for (int k = 0; k < 16; k++) mx = fmaxf(mx, qs * qkv[o * 16 + k]);
        float sum = 0.f, y = 0.f;
        #pragma unroll
        for (int k = 0; k < 16; k++) {
            float e = __expf(qs * qkv[o * 16 + k] - mx);
            sum += e;
            y   += e * qkv[(16 + o) * 16 + k];
        }
        y /= sum;
        float g = 1.f / (1.f + __expf(-y));
        gates[b * 256 + o * 16 + s] = g;
    }
}

// Per-pixel: recompute vx channels, gate, 16->64 conv, + bias + residual.
__global__ __launch_bounds__(256) void out_kernel(const float* __restrict__ x,
                                                  const float* __restrict__ w1t,
                                                  const float* __restrict__ b1,
                                                  const float* __restrict__ w2,
                                                  const float* __restrict__ b2,
                                                  const float* __restrict__ gates,
                                                  float* __restrict__ out) {
    int bh = blockIdx.x;
    int b  = bh >> 8;      // 256 rows per batch
    int h  = bh & 255;
    int w  = threadIdx.x;  // 0..255
    int s  = (h & 3) * 4 + (w & 3);
    const float* xb = x   + (size_t)b * NC * HW + h * WW + w;
    float*       ob = out + (size_t)b * NC * HW + h * WW + w;

    __shared__ float gsh[256];
    gsh[w] = gates[b * 256 + w];
    __syncthreads();

    float xr[64];
    #pragma unroll
    for (int c = 0; c < 64; c++) xr[c] = xb[(size_t)c * HW];

    float fv[16];
    #pragma unroll
    for (int j = 0; j < 16; j++) fv[j] = b1[16 + j];
    #pragma unroll
    for (int c = 0; c < 64; c++) {
        float xc = xr[c];
        #pragma unroll
        for (int j = 0; j < 16; j++) fv[j] += w1t[c * 32 + 16 + j] * xc;
    }
    #pragma unroll
    for (int j = 0; j < 16; j++) {
        float v = fv[j] > 0.f ? fv[j] : 0.f;
        fv[j] = v * gsh[j * 16 + s];
    }
    #pragma unroll
    for (int o = 0; o < 64; o++) {
        float r = b2[o] + xr[o];
        #pragma unroll
        for (int j = 0; j < 16; j++) r += w2[o * 16 + j] * fv[j];
        ob[(size_t)o * HW] = r;
    }
}

extern "C" void kernel_launch(void* const* d_in, const int* in_sizes, int n_in,
                              void* d_out, int out_size, void* d_ws, size_t ws_size,
                              hipStream_t stream) {
    const float* x  = (const float*)d_in[0];
    const float* w1 = (const float*)d_in[1];
    const float* b1 = (const float*)d_in[2];
    const float* w2 = (const float*)d_in[3];
    const float* b2 = (const float*)d_in[4];
    float* ws    = (float*)d_ws;
    float* w1t   = ws;
    float* stats = ws + 2048;
    float* gates = ws + 26624;
    float* out   = (float*)d_out;

    prep_kernel <<<1,    256, 0, stream>>>(w1, ws);
    stats_kernel<<<2048, 256, 0, stream>>>(x, w1t, b1, stats);
    attn_kernel <<<16,   512, 0, stream>>>(stats, gates);
    out_kernel  <<<4096, 256, 0, stream>>>(x, w1t, b1, w2, b2, gates, out);
}

// Round 8
// 248.914 us; speedup vs baseline: 1.0039x; 1.0039x over previous
//
#include <hip/hip_runtime.h>
#include <hip/hip_bf16.h>

#define NB 16
#define NC 64
#define C2 32
#define C4 16
#define HH 256
#define WW 256
#define HW (HH*WW)          // 65536

typedef unsigned short u16;
typedef u16 u16x8 __attribute__((ext_vector_type(8)));

// ws layout (floats):
//   [0, 2048)        w1T   : w1T[c*32+o] = w1[o*64+c]
//   [2048, 10240)    qkv   : [b][ch32][s16]  (written by qkv_kernel)
//   [26624, 30720)   gates : [b][o16][s16]   (per-b stride 256)
//   [32768, ...)     y     : bf16 [b][o32][s16][l4096]  (67.1 MB)

__global__ __launch_bounds__(256) void prep_kernel(const float* __restrict__ w1,
                                                   float* __restrict__ ws) {
    int t = threadIdx.x;
    for (int i = t; i < 2048; i += 256) {
        int o = i >> 6, c = i & 63;
        ws[c * 32 + o] = w1[i];
    }
}

// A: pure streaming map. conv 64->32 + relu, write bf16 y in moment-friendly
// transposed layout. Same proven structure as out_kernel (register load queue,
// no barriers, no persistent state).
__global__ __launch_bounds__(256) void conv_kernel(const float* __restrict__ x,
                                                   const float* __restrict__ w1t,
                                                   const float* __restrict__ b1,
                                                   u16* __restrict__ y) {
    int bh = blockIdx.x;
    int b  = bh >> 8;      // 256 rows per batch
    int h  = bh & 255;
    int w  = threadIdx.x;  // 0..255
    const float* xb = x + (size_t)b * NC * HW + h * WW + w;

    float xr[64];
    #pragma unroll
    for (int c = 0; c < 64; c++) xr[c] = xb[(size_t)c * HW];

    float acc[32];
    #pragma unroll
    for (int o = 0; o < 32; o++) acc[o] = b1[o];
    #pragma unroll
    for (int c = 0; c < 64; c++) {
        float xc = xr[c];
        #pragma unroll
        for (int o = 0; o < 32; o++) acc[o] += w1t[c * 32 + o] * xc;
    }

    int s = (h & 3) * 4 + (w & 3);
    int l = (h >> 2) * 64 + (w >> 2);
    u16* yb = y + (size_t)b * (32 * 16 * 4096) + s * 4096 + l;
    #pragma unroll
    for (int o = 0; o < 32; o++) {
        float v = fmaxf(acc[o], 0.f);
        __hip_bfloat16 hv = __float2bfloat16(v);
        yb[(size_t)o * 65536] = *reinterpret_cast<u16*>(&hv);
    }
}

// B: per (b,ch,s) group = 4096 contiguous bf16. One wave per group; ushort8
// loads, 3 regs of state, butterfly over 64 lanes; lane 0 writes qkv = mu+m3.
__global__ __launch_bounds__(256) void qkv_kernel(const u16* __restrict__ y,
                                                  float* __restrict__ qkv) {
    int g    = blockIdx.x * 4 + (threadIdx.x >> 6);   // group = b*512 + ch*16 + s
    int lane = threadIdx.x & 63;
    const u16x8* p = (const u16x8*)(y + (size_t)g * 4096);

    float S1 = 0.f, S2 = 0.f, S3 = 0.f;
    #pragma unroll
    for (int k = 0; k < 8; k++) {
        u16x8 v8 = p[k * 64 + lane];
        #pragma unroll
        for (int j = 0; j < 8; j++) {
            unsigned int bits = (unsigned int)v8[j] << 16;
            float v = __builtin_bit_cast(float, bits);
            S1 += v;
            float pw = v * v;
            S2 += pw;
            S3 += pw * v;
        }
    }
    #pragma unroll
    for (int m = 1; m <= 32; m <<= 1) {
        S1 += __shfl_xor(S1, m);
        S2 += __shfl_xor(S2, m);
        S3 += __shfl_xor(S3, m);
    }
    if (lane == 0) {
        float mu = S1 * (1.f / 4096.f);
        float m3 = (S3 - 3.f * mu * S2 + 2.f * 4096.f * mu * mu * mu) * (1.f / 16.f);
        qkv[g] = mu + m3;
    }
}

// Tiny attention: softmax(q q^T) @ v; gate = sigmoid(y).
__global__ __launch_bounds__(512) void attn_kernel(const float* __restrict__ qkvg,
                                                   float* __restrict__ gates) {
    int b = blockIdx.x;
    int t = threadIdx.x;
    __shared__ float qkv[512];
    qkv[t] = qkvg[b * 512 + t];
    __syncthreads();
    if (t < 256) {
        int o = t >> 4, s = t & 15;
        float qs = qkv[o * 16 + s];
        float mx = -1e30f;
        #pragma unroll
        for (int k = 0; k < 16; k++) mx = fmaxf(mx, qs * qkv[o * 16 + k]);
        float sum = 0.f, y = 0.f;
        #pragma unroll
        for (int k = 0; k < 16; k++) {
            float e = __expf(qs * qkv[o * 16 + k] - mx);
            sum += e;
            y   += e * qkv[(16 + o) * 16 + k];
        }
        y /= sum;
        float g = 1.f / (1.f + __expf(-y));
        gates[b * 256 + o * 16 + s] = g;
    }
}

// Per-pixel: recompute vx channels, gate, 16->64 conv, + bias + residual.
__global__ __launch_bounds__(256) void out_kernel(const float* __restrict__ x,
                                                  const float* __restrict__ w1t,
                                                  const float* __restrict__ b1,
                                                  const float* __restrict__ w2,
                                                  const float* __restrict__ b2,
                                                  const float* __restrict__ gates,
                                                  float* __restrict__ out) {
    int bh = blockIdx.x;
    int b  = bh >> 8;      // 256 rows per batch
    int h  = bh & 255;
    int w  = threadIdx.x;  // 0..255
    int s  = (h & 3) * 4 + (w & 3);
    const float* xb = x   + (size_t)b * NC * HW + h * WW + w;
    float*       ob = out + (size_t)b * NC * HW + h * WW + w;

    __shared__ float gsh[256];
    gsh[w] = gates[b * 256 + w];
    __syncthreads();

    float xr[64];
    #pragma unroll
    for (int c = 0; c < 64; c++) xr[c] = xb[(size_t)c * HW];

    float fv[16];
    #pragma unroll
    for (int j = 0; j < 16; j++) fv[j] = b1[16 + j];
    #pragma unroll
    for (int c = 0; c < 64; c++) {
        float xc = xr[c];
        #pragma unroll
        for (int j = 0; j < 16; j++) fv[j] += w1t[c * 32 + 16 + j] * xc;
    }
    #pragma unroll
    for (int j = 0; j < 16; j++) {
        float v = fv[j] > 0.f ? fv[j] : 0.f;
        fv[j] = v * gsh[j * 16 + s];
    }
    #pragma unroll
    for (int o = 0; o < 64; o++) {
        float r = b2[o] + xr[o];
        #pragma unroll
        for (int j = 0; j < 16; j++) r += w2[o * 16 + j] * fv[j];
        ob[(size_t)o * HW] = r;
    }
}

extern "C" void kernel_launch(void* const* d_in, const int* in_sizes, int n_in,
                              void* d_out, int out_size, void* d_ws, size_t ws_size,
                              hipStream_t stream) {
    const float* x  = (const float*)d_in[0];
    const float* w1 = (const float*)d_in[1];
    const float* b1 = (const float*)d_in[2];
    const float* w2 = (const float*)d_in[3];
    const float* b2 = (const float*)d_in[4];
    float* ws    = (float*)d_ws;
    float* w1t   = ws;
    float* qkv   = ws + 2048;
    float* gates = ws + 26624;
    u16*   y     = (u16*)(ws + 32768);
    float* out   = (float*)d_out;

    prep_kernel<<<1,    256, 0, stream>>>(w1, ws);
    conv_kernel<<<4096, 256, 0, stream>>>(x, w1t, b1, y);
    qkv_kernel <<<2048, 256, 0, stream>>>(y, qkv);
    attn_kernel<<<16,   512, 0, stream>>>(qkv, gates);
    out_kernel <<<4096, 256, 0, stream>>>(x, w1t, b1, w2, b2, gates, out);
}

// Round 9
// 248.123 us; speedup vs baseline: 1.0071x; 1.0032x over previous
//
#include <hip/hip_runtime.h>
#include <hip/hip_bf16.h>

#define NB 16
#define NC 64
#define C2 32
#define C4 16
#define HH 256
#define WW 256
#define HW (HH*WW)          // 65536

typedef unsigned short u16;
typedef u16 u16x8 __attribute__((ext_vector_type(8)));

// ws layout (floats):
//   [0, 2048)        w1T   : w1T[c*32+o] = w1[o*64+c]
//   [2048, 10240)    qkv   : [b][ch32][s16]
//   [26624, 30720)   gates : [b][o16][s16]   (per-b stride 256)
//   [32768, ...)     y     : bf16 [b][o32][h256][w256]  (67.1 MB)

__global__ __launch_bounds__(256) void prep_kernel(const float* __restrict__ w1,
                                                   float* __restrict__ ws) {
    int t = threadIdx.x;
    for (int i = t; i < 2048; i += 256) {
        int o = i >> 6, c = i & 63;
        ws[c * 32 + o] = w1[i];
    }
}

// A: pure streaming map. conv 64->32 + relu, write bf16 y in x-identical
// [b][o][h][w] layout -> every wave store is 128B contiguous (out_kernel's
// proven pattern). No barriers, no persistent state.
__global__ __launch_bounds__(256) void conv_kernel(const float* __restrict__ x,
                                                   const float* __restrict__ w1t,
                                                   const float* __restrict__ b1,
                                                   u16* __restrict__ y) {
    int bh = blockIdx.x;
    int b  = bh >> 8;      // 256 rows per batch
    int h  = bh & 255;
    int w  = threadIdx.x;  // 0..255
    const float* xb = x + (size_t)b * NC * HW + h * WW + w;

    float xr[64];
    #pragma unroll
    for (int c = 0; c < 64; c++) xr[c] = xb[(size_t)c * HW];

    float acc[32];
    #pragma unroll
    for (int o = 0; o < 32; o++) acc[o] = b1[o];
    #pragma unroll
    for (int c = 0; c < 64; c++) {
        float xc = xr[c];
        #pragma unroll
        for (int o = 0; o < 32; o++) acc[o] += w1t[c * 32 + o] * xc;
    }

    u16* yb = y + (size_t)b * (32 * HW) + h * WW + w;
    #pragma unroll
    for (int o = 0; o < 32; o++) {
        float v = fmaxf(acc[o], 0.f);
        __hip_bfloat16 hv = __float2bfloat16(v);
        yb[(size_t)o * HW] = *reinterpret_cast<u16*>(&hv);
    }
}

// B: block = one (b,o) plane (64KB of bf16). Wave-inst reads 1KB contiguous
// (u16x8/lane). Per thread: h%4 fixed, w%4 = j&3 static -> S[3][4] registers.
// Butterfly over 32-lane halves, LDS combine, threads 0..15 write qkv = mu+m3.
__global__ __launch_bounds__(256) void qkv_kernel(const u16* __restrict__ y,
                                                  float* __restrict__ qkv) {
    int g    = blockIdx.x;            // b*32 + o
    int t    = threadIdx.x;
    int wave = t >> 6;
    int lane = t & 63;
    int half = lane >> 5;
    int hres = (wave * 2 + half) & 3; // this thread's fixed h%4
    const u16x8* p = (const u16x8*)(y + (size_t)g * HW);

    float S1[4], S2[4], S3[4];
    #pragma unroll
    for (int j = 0; j < 4; j++) { S1[j] = 0.f; S2[j] = 0.f; S3[j] = 0.f; }

    #pragma unroll 4
    for (int k = 0; k < 32; ++k) {
        int h = k * 8 + wave * 2 + half;
        u16x8 v8 = p[h * 32 + (lane & 31)];
        #pragma unroll
        for (int j = 0; j < 8; j++) {
            unsigned int bits = (unsigned int)v8[j] << 16;
            float v = __builtin_bit_cast(float, bits);
            int wr = j & 3;
            S1[wr] += v;
            float pw = v * v;
            S2[wr] += pw;
            S3[wr] += pw * v;
        }
    }

    // Sum the 32 lanes sharing this h-residue (lanes stay within their half).
    #pragma unroll
    for (int wr = 0; wr < 4; wr++) {
        #pragma unroll
        for (int m = 1; m <= 16; m <<= 1) {
            S1[wr] += __shfl_xor(S1[wr], m);
            S2[wr] += __shfl_xor(S2[wr], m);
            S3[wr] += __shfl_xor(S3[wr], m);
        }
    }

    __shared__ float red[2][4][4][3];   // [src][hres][wres][stat]
    if ((lane & 31) == 0) {
        int src = wave >> 1;
        #pragma unroll
        for (int wr = 0; wr < 4; wr++) {
            red[src][hres][wr][0] = S1[wr];
            red[src][hres][wr][1] = S2[wr];
            red[src][hres][wr][2] = S3[wr];
        }
    }
    __syncthreads();
    if (t < 16) {
        int hr = t >> 2, wr = t & 3;
        float s1 = red[0][hr][wr][0] + red[1][hr][wr][0];
        float s2 = red[0][hr][wr][1] + red[1][hr][wr][1];
        float s3 = red[0][hr][wr][2] + red[1][hr][wr][2];
        float mu = s1 * (1.f / 4096.f);
        float m3 = (s3 - 3.f * mu * s2 + 2.f * 4096.f * mu * mu * mu) * (1.f / 16.f);
        qkv[g * 16 + t] = mu + m3;     // t == hr*4+wr == s
    }
}

// Tiny attention: softmax(q q^T) @ v; gate = sigmoid(y).
__global__ __launch_bounds__(512) void attn_kernel(const float* __restrict__ qkvg,
                                                   float* __restrict__ gates) {
    int b = blockIdx.x;
    int t = threadIdx.x;
    __shared__ float qkv[512];
    qkv[t] = qkvg[b * 512 + t];
    __syncthreads();
    if (t < 256) {
        int o = t >> 4, s = t & 15;
        float qs = qkv[o * 16 + s];
        float mx = -1e30f;
        #pragma unroll
        for (int k = 0; k < 16; k++) mx = fmaxf(mx, qs * qkv[o * 16 + k]);
        float sum = 0.f, y = 0.f;
        #pragma unroll
        for (int k = 0; k < 16; k++) {
            float e = __expf(qs * qkv[o * 16 + k] - mx);
            sum += e;
            y   += e * qkv[(16 + o) * 16 + k];
        }
        y /= sum;
        float g = 1.f / (1.f + __expf(-y));
        gates[b * 256 + o * 16 + s] = g;
    }
}

// Per-pixel: recompute vx channels, gate, 16->64 conv, + bias + residual.
__global__ __launch_bounds__(256) void out_kernel(const float* __restrict__ x,
                                                  const float* __restrict__ w1t,
                                                  const float* __restrict__ b1,
                                                  const float* __restrict__ w2,
                                                  const float* __restrict__ b2,
                                                  const float* __restrict__ gates,
                                                  float* __restrict__ out) {
    int bh = blockIdx.x;
    int b  = bh >> 8;      // 256 rows per batch
    int h  = bh & 255;
    int w  = threadIdx.x;  // 0..255
    int s  = (h & 3) * 4 + (w & 3);
    const float* xb = x   + (size_t)b * NC * HW + h * WW + w;
    float*       ob = out + (size_t)b * NC * HW + h * WW + w;

    __shared__ float gsh[256];
    gsh[w] = gates[b * 256 + w];
    __syncthreads();

    float xr[64];
    #pragma unroll
    for (int c = 0; c < 64; c++) xr[c] = xb[(size_t)c * HW];

    float fv[16];
    #pragma unroll
    for (int j = 0; j < 16; j++) fv[j] = b1[16 + j];
    #pragma unroll
    for (int c = 0; c < 64; c++) {
        float xc = xr[c];
        #pragma unroll
        for (int j = 0; j < 16; j++) fv[j] += w1t[c * 32 + 16 + j] * xc;
    }
    #pragma unroll
    for (int j = 0; j < 16; j++) {
        float v = fv[j] > 0.f ? fv[j] : 0.f;
        fv[j] = v * gsh[j * 16 + s];
    }
    #pragma unroll
    for (int o = 0; o < 64; o++) {
        float r = b2[o] + xr[o];
        #pragma unroll
        for (int j = 0; j < 16; j++) r += w2[o * 16 + j] * fv[j];
        ob[(size_t)o * HW] = r;
    }
}

extern "C" void kernel_launch(void* const* d_in, const int* in_sizes, int n_in,
                              void* d_out, int out_size, void* d_ws, size_t ws_size,
                              hipStream_t stream) {
    const float* x  = (const float*)d_in[0];
    const float* w1 = (const float*)d_in[1];
    const float* b1 = (const float*)d_in[2];
    const float* w2 = (const float*)d_in[3];
    const float* b2 = (const float*)d_in[4];
    float* ws    = (float*)d_ws;
    float* w1t   = ws;
    float* qkv   = ws + 2048;
    float* gates = ws + 26624;
    u16*   y     = (u16*)(ws + 32768);
    float* out   = (float*)d_out;

    prep_kernel<<<1,    256, 0, stream>>>(w1, ws);
    conv_kernel<<<4096, 256, 0, stream>>>(x, w1t, b1, y);
    qkv_kernel <<<512,  256, 0, stream>>>(y, qkv);
    attn_kernel<<<16,   512, 0, stream>>>(qkv, gates);
    out_kernel <<<4096, 256, 0, stream>>>(x, w1t, b1, w2, b2, gates, out);
}

// Round 10
// 245.537 us; speedup vs baseline: 1.0177x; 1.0105x over previous
//
#include <hip/hip_runtime.h>
#include <hip/hip_bf16.h>

#define NB 16
#define NC 64
#define C2 32
#define C4 16
#define HH 256
#define WW 256
#define HW (HH*WW)          // 65536

typedef unsigned short u16;
typedef u16 u16x8 __attribute__((ext_vector_type(8)));

// ws layout (floats):
//   [0, 2048)        w1T   : w1T[c*32+o] = w1[o*64+c]
//   [2048, 10240)    qkv   : [b][ch32][s16]
//   [26624, 30720)   gates : [b][o16][s16]   (per-b stride 256)
//   [32768, ...)     y     : bf16 [b][o32][h256][w256]  (67.1 MB)

__global__ __launch_bounds__(256) void prep_kernel(const float* __restrict__ w1,
                                                   float* __restrict__ ws) {
    int t = threadIdx.x;
    for (int i = t; i < 2048; i += 256) {
        int o = i >> 6, c = i & 63;
        ws[c * 32 + o] = w1[i];
    }
}

// A: streaming map, out_kernel-identical register profile: xr[64] + acc[16].
// Two sequential 16-channel passes (unroll 1 so they never merge into acc[32]).
__global__ __launch_bounds__(256) void conv_kernel(const float* __restrict__ x,
                                                   const float* __restrict__ w1t,
                                                   const float* __restrict__ b1,
                                                   u16* __restrict__ y) {
    int bh = blockIdx.x;
    int b  = bh >> 8;      // 256 rows per batch
    int h  = bh & 255;
    int w  = threadIdx.x;  // 0..255
    const float* xb = x + (size_t)b * NC * HW + h * WW + w;

    float xr[64];
    #pragma unroll
    for (int c = 0; c < 64; c++) xr[c] = xb[(size_t)c * HW];

    u16* yb = y + (size_t)b * (32 * HW) + h * WW + w;

    #pragma unroll 1
    for (int half = 0; half < 2; ++half) {
        float acc[16];
        #pragma unroll
        for (int j = 0; j < 16; j++) acc[j] = b1[half * 16 + j];
        #pragma unroll
        for (int c = 0; c < 64; c++) {
            float xc = xr[c];
            #pragma unroll
            for (int j = 0; j < 16; j++) acc[j] += w1t[c * 32 + half * 16 + j] * xc;
        }
        #pragma unroll
        for (int j = 0; j < 16; j++) {
            float v = fmaxf(acc[j], 0.f);
            __hip_bfloat16 hv = __float2bfloat16(v);
            yb[(size_t)(half * 16 + j) * HW] = *reinterpret_cast<u16*>(&hv);
        }
    }
}

// B: block = one (b,o) plane (64KB of bf16). Wave-inst reads 1KB contiguous
// (u16x8/lane). Per thread: h%4 fixed, w%4 = j&3 static -> S[3][4] registers.
// Butterfly over 32-lane halves, LDS combine, threads 0..15 write qkv = mu+m3.
__global__ __launch_bounds__(256) void qkv_kernel(const u16* __restrict__ y,
                                                  float* __restrict__ qkv) {
    int g    = blockIdx.x;            // b*32 + o
    int t    = threadIdx.x;
    int wave = t >> 6;
    int lane = t & 63;
    int half = lane >> 5;
    int hres = (wave * 2 + half) & 3; // this thread's fixed h%4
    const u16x8* p = (const u16x8*)(y + (size_t)g * HW);

    float S1[4], S2[4], S3[4];
    #pragma unroll
    for (int j = 0; j < 4; j++) { S1[j] = 0.f; S2[j] = 0.f; S3[j] = 0.f; }

    #pragma unroll 4
    for (int k = 0; k < 32; ++k) {
        int h = k * 8 + wave * 2 + half;
        u16x8 v8 = p[h * 32 + (lane & 31)];
        #pragma unroll
        for (int j = 0; j < 8; j++) {
            unsigned int bits = (unsigned int)v8[j] << 16;
            float v = __builtin_bit_cast(float, bits);
            int wr = j & 3;
            S1[wr] += v;
            float pw = v * v;
            S2[wr] += pw;
            S3[wr] += pw * v;
        }
    }

    // Sum the 32 lanes sharing this h-residue (lanes stay within their half).
    #pragma unroll
    for (int wr = 0; wr < 4; wr++) {
        #pragma unroll
        for (int m = 1; m <= 16; m <<= 1) {
            S1[wr] += __shfl_xor(S1[wr], m);
            S2[wr] += __shfl_xor(S2[wr], m);
            S3[wr] += __shfl_xor(S3[wr], m);
        }
    }

    __shared__ float red[2][4][4][3];   // [src][hres][wres][stat]
    if ((lane & 31) == 0) {
        int src = wave >> 1;
        #pragma unroll
        for (int wr = 0; wr < 4; wr++) {
            red[src][hres][wr][0] = S1[wr];
            red[src][hres][wr][1] = S2[wr];
            red[src][hres][wr][2] = S3[wr];
        }
    }
    __syncthreads();
    if (t < 16) {
        int hr = t >> 2, wr = t & 3;
        float s1 = red[0][hr][wr][0] + red[1][hr][wr][0];
        float s2 = red[0][hr][wr][1] + red[1][hr][wr][1];
        float s3 = red[0][hr][wr][2] + red[1][hr][wr][2];
        float mu = s1 * (1.f / 4096.f);
        float m3 = (s3 - 3.f * mu * s2 + 2.f * 4096.f * mu * mu * mu) * (1.f / 16.f);
        qkv[g * 16 + t] = mu + m3;     // t == hr*4+wr == s
    }
}

// Tiny attention: softmax(q q^T) @ v; gate = sigmoid(y).
__global__ __launch_bounds__(512) void attn_kernel(const float* __restrict__ qkvg,
                                                   float* __restrict__ gates) {
    int b = blockIdx.x;
    int t = threadIdx.x;
    __shared__ float qkv[512];
    qkv[t] = qkvg[b * 512 + t];
    __syncthreads();
    if (t < 256) {
        int o = t >> 4, s = t & 15;
        float qs = qkv[o * 16 + s];
        float mx = -1e30f;
        #pragma unroll
        for (int k = 0; k < 16; k++) mx = fmaxf(mx, qs * qkv[o * 16 + k]);
        float sum = 0.f, y = 0.f;
        #pragma unroll
        for (int k = 0; k < 16; k++) {
            float e = __expf(qs * qkv[o * 16 + k] - mx);
            sum += e;
            y   += e * qkv[(16 + o) * 16 + k];
        }
        y /= sum;
        float g = 1.f / (1.f + __expf(-y));
        gates[b * 256 + o * 16 + s] = g;
    }
}

// Per-pixel: recompute vx channels, gate, 16->64 conv, + bias + residual.
__global__ __launch_bounds__(256) void out_kernel(const float* __restrict__ x,
                                                  const float* __restrict__ w1t,
                                                  const float* __restrict__ b1,
                                                  const float* __restrict__ w2,
                                                  const float* __restrict__ b2,
                                                  const float* __restrict__ gates,
                                                  float* __restrict__ out) {
    int bh = blockIdx.x;
    int b  = bh >> 8;      // 256 rows per batch
    int h  = bh & 255;
    int w  = threadIdx.x;  // 0..255
    int s  = (h & 3) * 4 + (w & 3);
    const float* xb = x   + (size_t)b * NC * HW + h * WW + w;
    float*       ob = out + (size_t)b * NC * HW + h * WW + w;

    __shared__ float gsh[256];
    gsh[w] = gates[b * 256 + w];
    __syncthreads();

    float xr[64];
    #pragma unroll
    for (int c = 0; c < 64; c++) xr[c] = xb[(size_t)c * HW];

    float fv[16];
    #pragma unroll
    for (int j = 0; j < 16; j++) fv[j] = b1[16 + j];
    #pragma unroll
    for (int c = 0; c < 64; c++) {
        float xc = xr[c];
        #pragma unroll
        for (int j = 0; j < 16; j++) fv[j] += w1t[c * 32 + 16 + j] * xc;
    }
    #pragma unroll
    for (int j = 0; j < 16; j++) {
        float v = fv[j] > 0.f ? fv[j] : 0.f;
        fv[j] = v * gsh[j * 16 + s];
    }
    #pragma unroll
    for (int o = 0; o < 64; o++) {
        float r = b2[o] + xr[o];
        #pragma unroll
        for (int j = 0; j < 16; j++) r += w2[o * 16 + j] * fv[j];
        ob[(size_t)o * HW] = r;
    }
}

extern "C" void kernel_launch(void* const* d_in, const int* in_sizes, int n_in,
                              void* d_out, int out_size, void* d_ws, size_t ws_size,
                              hipStream_t stream) {
    const float* x  = (const float*)d_in[0];
    const float* w1 = (const float*)d_in[1];
    const float* b1 = (const float*)d_in[2];
    const float* w2 = (const float*)d_in[3];
    const float* b2 = (const float*)d_in[4];
    float* ws    = (float*)d_ws;
    float* w1t   = ws;
    float* qkv   = ws + 2048;
    float* gates = ws + 26624;
    u16*   y     = (u16*)(ws + 32768);
    float* out   = (float*)d_out;

    prep_kernel<<<1,    256, 0, stream>>>(w1, ws);
    conv_kernel<<<4096, 256, 0, stream>>>(x, w1t, b1, y);
    qkv_kernel <<<512,  256, 0, stream>>>(y, qkv);
    attn_kernel<<<16,   512, 0, stream>>>(qkv, gates);
    out_kernel <<<4096, 256, 0, stream>>>(x, w1t, b1, w2, b2, gates, out);
}